// Round 1
// baseline (478.798 us; speedup 1.0000x reference)
//
#include <hip/hip_runtime.h>

// IndRNN (recurrent-only): h_t = relu(x_t + w_hh * h_{t-1})
// x: [T=2048, B=64, H=512] fp32, weight_hh: [H] fp32 (~uniform[0,1) => w >= 0).
//
// Key identity (requires w >= 0, which holds): the step map
//   f_t(h) = max(0, x_t + w*h)
// is closed under composition in the family F(h) = max(C, B + S*h), C,S >= 0:
//   compose step t onto F: C' = max(0, x_t + w*C); B' = x_t + w*B; S' = w*S
// => per-chain recurrence becomes an associative scan. We split T=2048 into
// WAVES=8 windows of LWIN=256, one wave per window:
//   phase 1: each lane computes its window composite (C,B,S)   [reads x]
//   LDS scan: h_start(w) = F_{w-1}( ... F_0(0) )               [<=7 composes]
//   phase 2: exact reference recurrence from h_start, stores   [re-reads x]
// Wave 0 has h_start=0 a priori -> stores during phase 1, skips phase 2.
// Block = 8 waves x 64 consecutive chains => 512 blocks x 512 threads
// = 16 waves/CU (vs 2 before). All global accesses are 256B/wave coalesced.

#define HIDDEN 512
#define SEQ 2048
#define BATCH 64

constexpr int STRIDE = BATCH * HIDDEN;  // element stride between t and t+1
constexpr int CHAINS = BATCH * HIDDEN;  // 32768 independent chains
constexpr int WAVES = 8;                // waves (T-windows) per block
constexpr int BLOCK = WAVES * 64;       // 512 threads
constexpr int LWIN = SEQ / WAVES;       // 256 timesteps per window
constexpr int DEPTH = 16;               // prefetch depth per buffer

// Reference-exact recurrence + store (used by wave 0 phase 1 and by phase 2).
template <bool PF>
__device__ __forceinline__ void rec_chunk(float& hv, const float wh,
                                          const float (&cur)[DEPTH],
                                          float (&nxt)[DEPTH],
                                          const float* __restrict__ xn,
                                          float* __restrict__ o) {
#pragma unroll
  for (int i = 0; i < DEPTH; ++i) {
    if (PF) nxt[i] = __builtin_nontemporal_load(xn + (long)i * STRIDE);
    hv = fmaxf(0.0f, fmaf(wh, hv, cur[i]));  // same ops as reference
    __builtin_nontemporal_store(hv, o + (long)i * STRIDE);
  }
}

// Composite accumulation: (C,B,S) <- step(x) o (C,B,S).  3 independent chains
// per lane -> the serial latency of each hides under the others.
template <bool PF>
__device__ __forceinline__ void comp_chunk(float& C, float& Bv, float& Sv,
                                           const float wh,
                                           const float (&cur)[DEPTH],
                                           float (&nxt)[DEPTH],
                                           const float* __restrict__ xn) {
#pragma unroll
  for (int i = 0; i < DEPTH; ++i) {
    if (PF) nxt[i] = cur ? 0.0f : 0.0f;  // placeholder, replaced below
  }
}

// (real definition; the dummy above is not used — see comp_run)
template <bool PF>
__device__ __forceinline__ void comp_chunk2(float& C, float& Bv, float& Sv,
                                            const float wh,
                                            const float (&cur)[DEPTH],
                                            float (&nxt)[DEPTH],
                                            const float* __restrict__ xn) {
#pragma unroll
  for (int i = 0; i < DEPTH; ++i) {
    if (PF) nxt[i] = xn[(long)i * STRIDE];  // regular load: let L2/L3 retain x
    const float xv = cur[i];
    C = fmaxf(0.0f, fmaf(wh, C, xv));
    Bv = fmaf(wh, Bv, xv);
    Sv *= wh;
  }
}

__global__ __launch_bounds__(BLOCK) void indrnn_scan(
    const float* __restrict__ x, const float* __restrict__ w,
    float* __restrict__ out) {
  __shared__ float sC[WAVES][64];
  __shared__ float sB[WAVES][64];
  __shared__ float sS[WAVES][64];

  const int lane = threadIdx.x & 63;
  const int wv = threadIdx.x >> 6;               // window index 0..7
  const int chain = blockIdx.x * 64 + lane;      // b*HIDDEN + h (64 | HIDDEN)
  const float wh = w[chain & (HIDDEN - 1)];

  const long base = (long)(wv * LWIN) * STRIDE + chain;
  const float* xp = x + base;
  float* op = out + base;

  float bufA[DEPTH], bufB[DEPTH];
#pragma unroll
  for (int i = 0; i < DEPTH; ++i) bufA[i] = xp[(long)i * STRIDE];

  if (wv == 0) {
    // h_start = 0 is known: produce final outputs directly during phase 1.
    float hv = 0.0f;
    int t = 0;
#pragma unroll 1
    for (; t + 2 * DEPTH < LWIN; t += 2 * DEPTH) {
      rec_chunk<true>(hv, wh, bufA, bufB, xp + (long)(t + DEPTH) * STRIDE,
                      op + (long)t * STRIDE);
      rec_chunk<true>(hv, wh, bufB, bufA, xp + (long)(t + 2 * DEPTH) * STRIDE,
                      op + (long)(t + DEPTH) * STRIDE);
    }
    rec_chunk<true>(hv, wh, bufA, bufB, xp + (long)(t + DEPTH) * STRIDE,
                    op + (long)t * STRIDE);
    rec_chunk<false>(hv, wh, bufB, bufA, nullptr,
                     op + (long)(t + DEPTH) * STRIDE);
    sC[0][lane] = hv;  // F_0(0); waves 1.. start their scan from this
  } else {
    float C = 0.0f, Bv = 0.0f, Sv = 1.0f;
    int t = 0;
#pragma unroll 1
    for (; t + 2 * DEPTH < LWIN; t += 2 * DEPTH) {
      comp_chunk2<true>(C, Bv, Sv, wh, bufA, bufB,
                        xp + (long)(t + DEPTH) * STRIDE);
      comp_chunk2<true>(C, Bv, Sv, wh, bufB, bufA,
                        xp + (long)(t + 2 * DEPTH) * STRIDE);
    }
    comp_chunk2<true>(C, Bv, Sv, wh, bufA, bufB,
                      xp + (long)(t + DEPTH) * STRIDE);
    comp_chunk2<false>(C, Bv, Sv, wh, bufB, bufA, nullptr);

    // Issue phase-2 priming loads before the barrier so their latency hides
    // under the barrier + scan.
#pragma unroll
    for (int i = 0; i < DEPTH; ++i)
      bufA[i] = __builtin_nontemporal_load(xp + (long)i * STRIDE);

    sC[wv][lane] = C;
    sB[wv][lane] = Bv;
    sS[wv][lane] = Sv;
  }

  __syncthreads();  // convergent: every thread reaches exactly this barrier

  if (wv == 0) return;

  // Scan window composites to get this window's true h_start.
  // Lane-contiguous LDS rows: 2 lanes/bank -> conflict-free.
  float hv = sC[0][lane];
  for (int k = 1; k < wv; ++k)
    hv = fmaxf(sC[k][lane], fmaf(sS[k][lane], hv, sB[k][lane]));

  // Phase 2: exact recurrence from h_start, write outputs.
  int t = 0;
#pragma unroll 1
  for (; t + 2 * DEPTH < LWIN; t += 2 * DEPTH) {
    rec_chunk<true>(hv, wh, bufA, bufB, xp + (long)(t + DEPTH) * STRIDE,
                    op + (long)t * STRIDE);
    rec_chunk<true>(hv, wh, bufB, bufA, xp + (long)(t + 2 * DEPTH) * STRIDE,
                    op + (long)(t + DEPTH) * STRIDE);
  }
  rec_chunk<true>(hv, wh, bufA, bufB, xp + (long)(t + DEPTH) * STRIDE,
                  op + (long)t * STRIDE);
  rec_chunk<false>(hv, wh, bufB, bufA, nullptr,
                   op + (long)(t + DEPTH) * STRIDE);
}

extern "C" void kernel_launch(void* const* d_in, const int* in_sizes, int n_in,
                              void* d_out, int out_size, void* d_ws,
                              size_t ws_size, hipStream_t stream) {
  const float* x = (const float*)d_in[0];
  const float* w = (const float*)d_in[1];
  float* out = (float*)d_out;
  indrnn_scan<<<CHAINS / 64, BLOCK, 0, stream>>>(x, w, out);
}